// Round 7
// baseline (1501.730 us; speedup 1.0000x reference)
//
#include <hip/hip_runtime.h>

// ---------------- problem constants ----------------
// VOCAB=50000, E=128, H=256, B=64, M=50, S=20, SQ=20, SEQEND=2, HOPS=3
//
// R6 -> R7: single-WG chains — cross-CU sync eliminated.
//  - R5/R6 were latency-bound on the agent-scope round trip (~10-15 us/step
//    regardless of traffic). Now: one chain = one 1024-thread WG (16 waves,
//    4/SIMD, one CU). h lives in an LDS double buffer; the per-step exchange
//    is ONE __syncthreads(). No atomics, no flags, no spins -> no hang modes.
//  - Weights (576 KB bf16) can't fit LDS (160 KB) or RF at the 128-VGPR cap,
//    so they stream from L2 each step. wconv_k pre-converts fp32 weights into
//    bf16 B-fragment order once, so the K-loop issues invariant-address
//    dwordx4 loads only (~576 KB/step/CU ~ 2.6k cy, hidden under MFMA).
//  - MFMA floor: 2304 mfma_16x16x32_bf16 per step per CU ~ 11.2k cy ~ 4.7us;
//    32-step chains -> ~150 us predicted for gru_k.
//  - warm-start truncation unchanged (warm=12, verified at bf16 noise floor).

typedef __attribute__((ext_vector_type(8))) short bf16x8;
typedef __attribute__((ext_vector_type(4))) float f32x4;
typedef __attribute__((ext_vector_type(4))) unsigned u32x4;

__device__ __forceinline__ unsigned short f2bf(float f) {
  union { float f; unsigned u; } v; v.f = f;
  unsigned x = v.u;
  return (unsigned short)((x + 0x7fffu + ((x >> 16) & 1u)) >> 16);
}

__device__ __forceinline__ float fsigmoid(float x) {
  return __builtin_amdgcn_rcpf(1.f + __expf(-x));
}
__device__ __forceinline__ float ftanh(float x) {
  return 1.f - 2.f * __builtin_amdgcn_rcpf(__expf(2.f * x) + 1.f);
}

// ---------------- eos index extraction ----------------
__global__ void idx_k(const int* __restrict__ story, const int* __restrict__ query,
                      int* __restrict__ idx_s, int* __restrict__ qidx) {
  int i = blockIdx.x * 256 + threadIdx.x;
  if (i < 3200) {                       // b*50+m
    const int* r = story + i * 20;
    int f = 19;
    for (int s = 19; s >= 0; --s) if (r[s] == 2) f = s;
    idx_s[i] = f;
  } else if (i < 3264) {
    int b = i - 3200;
    const int* r = query + b * 20;
    int f = 19;
    for (int s = 19; s >= 0; --s) if (r[s] == 2) f = s;
    qidx[b] = f;
  }
}

// ---------------- weight pre-convert: fp32 -> bf16 B-fragment order ----------------
// ih region: 16 slices x 3 gates x 4 kt x 256 uints  (49,152 uints)
// hh region: 16 slices x 3 gates x 8 kt x 256 uints  (98,304 uints)
// frag uint layout: lane*4 + w4; elements j=2*w4, 2*w4+1
// B element: w[(g*256 + slice*16 + (lane&15)) * K + kt*32 + (lane>>4)*8 + j]
__global__ void wconv_k(const float* __restrict__ w_ih, const float* __restrict__ w_hh,
                        unsigned* __restrict__ Bih_bf, unsigned* __restrict__ Bhh_bf) {
  int i = blockIdx.x * 256 + threadIdx.x;
  if (i < 49152) {
    int frag = i >> 8, u = i & 255;
    int lane = u >> 2, w4 = u & 3;
    int slice = frag / 12, r = frag % 12;
    int g = r >> 2, kt = r & 3;
    int row = g * 256 + slice * 16 + (lane & 15);
    int kb = kt * 32 + (lane >> 4) * 8 + 2 * w4;
    const float* p = w_ih + (size_t)row * 128 + kb;
    Bih_bf[i] = (unsigned)f2bf(p[0]) | ((unsigned)f2bf(p[1]) << 16);
  } else if (i < 147456) {
    int i2 = i - 49152;
    int frag = i2 >> 8, u = i2 & 255;
    int lane = u >> 2, w4 = u & 3;
    int slice = frag / 24, r = frag % 24;
    int g = r >> 3, kt = r & 7;
    int row = g * 256 + slice * 16 + (lane & 15);
    int kb = kt * 32 + (lane >> 4) * 8 + 2 * w4;
    const float* p = w_hh + (size_t)row * 256 + kb;
    Bhh_bf[i2] = (unsigned)f2bf(p[0]) | ((unsigned)f2bf(p[1]) << 16);
  }
}

// ---------------- embedding gather -> bf16 X buffers ----------------
// Xs: [1280][64 rows][128] bf16 (2 per uint) ; Xq: [20][64][128] bf16
__global__ void gather_k(const int* __restrict__ story, const int* __restrict__ query,
                         const float* __restrict__ embed,
                         unsigned* __restrict__ Xs, unsigned* __restrict__ Xq) {
  long long id = (long long)blockIdx.x * 256 + threadIdx.x;
  if (id < 5242880LL) {                 // 1280*64*64
    int e2 = (int)(id & 63);
    int m  = (int)((id >> 6) & 63);
    int t  = (int)(id >> 12);
    unsigned val = 0u;
    if (m < 50) {
      int b = t / 20, s = t - b * 20;
      int tok = story[(b * 50 + m) * 20 + s];
      const float* e = embed + (size_t)tok * 128 + e2 * 2;
      val = (unsigned)f2bf(e[0]) | ((unsigned)f2bf(e[1]) << 16);
    }
    Xs[id] = val;
  } else {
    long long id2 = id - 5242880LL;     // 20*64*64 = 81920
    int e2 = (int)(id2 & 63);
    int b  = (int)((id2 >> 6) & 63);
    int t  = (int)(id2 >> 12);
    int tok = query[b * 20 + t];
    const float* e = embed + (size_t)tok * 128 + e2 * 2;
    Xq[id2] = (unsigned)f2bf(e[0]) | ((unsigned)f2bf(e[1]) << 16);
  }
}

// ---------------- GRU: one chain per 1024-thread WG, h in LDS ----------------
__global__ __launch_bounds__(1024) void gru_k(
    const unsigned* __restrict__ Bih_bf, const unsigned* __restrict__ Bhh_bf,
    const float* __restrict__ b_ih, const float* __restrict__ b_hh,
    const unsigned* __restrict__ Xs, const unsigned* __restrict__ Xq,
    const int* __restrict__ idx_s, const int* __restrict__ qidx,
    float* __restrict__ mem_slots, float* __restrict__ real_q) {
  __shared__ unsigned s_h[2 * 8448];    // 2 parity x 64 rows x 132 uints (67.6 KB)
  __shared__ int s_idx[64];
  const int tid = threadIdx.x;
  const int p = blockIdx.x;             // chain 0..64 (64 = query)
  const bool isq = (p == 64);
  const int lane = tid & 63;
  const int wave = tid >> 6;            // col slice 0..15
  const int lo = lane & 15;
  const int quad = lane >> 4;
  const int col = wave * 16 + lo;
  const int T = isq ? 20 : (p == 0 ? 20 : 32);
  const int warm = (isq || p == 0) ? 0 : 12;
  const int tokBase = (isq || p == 0) ? 0 : p * 20 - 12;
  const unsigned* X = isq ? Xq : Xs;

  if (tid < 64) s_idx[tid] = isq ? qidx[tid] : (tid < 50 ? idx_s[p * 50 + tid] : -1);
  const float br  = b_ih[col]       + b_hh[col];
  const float bz  = b_ih[256 + col] + b_hh[256 + col];
  const float bin = b_ih[512 + col];
  const float bhn = b_hh[512 + col];
  __syncthreads();

  // invariant weight-fragment bases (uints)
  const unsigned* BihW = Bih_bf + (size_t)wave * 3072 + lane * 4;
  const unsigned* BhhW = Bhh_bf + (size_t)wave * 6144 + lane * 4;

  union U4 { u32x4 v4; bf16x8 v; };
  float h_own[4][4];
#pragma unroll
  for (int rt = 0; rt < 4; ++rt)
#pragma unroll
    for (int i = 0; i < 4; ++i) h_own[rt][i] = 0.f;

  for (int t = 0; t < T; ++t) {
    const unsigned* xt = X + (size_t)(tokBase + t) * 4096;
    f32x4 accr[4], accz[4], accn[4], acchn[4];
#pragma unroll
    for (int rt = 0; rt < 4; ++rt) {
      accr[rt] = (f32x4){0.f, 0.f, 0.f, 0.f};
      accz[rt] = (f32x4){0.f, 0.f, 0.f, 0.f};
      accn[rt] = (f32x4){0.f, 0.f, 0.f, 0.f};
      acchn[rt] = (f32x4){0.f, 0.f, 0.f, 0.f};
    }

    // ---- gi = x_t @ w_ih^T  (B streams from L2, A from global X) ----
#pragma unroll
    for (int kt = 0; kt < 4; ++kt) {
      U4 b0, b1, b2;
      b0.v4 = *(const u32x4*)(BihW + kt * 256);
      b1.v4 = *(const u32x4*)(BihW + (4 + kt) * 256);
      b2.v4 = *(const u32x4*)(BihW + (8 + kt) * 256);
#pragma unroll
      for (int rt = 0; rt < 4; ++rt) {
        U4 ax;
        ax.v4 = *(const u32x4*)(xt + (rt * 16 + lo) * 64 + kt * 16 + quad * 4);
        accr[rt] = __builtin_amdgcn_mfma_f32_16x16x32_bf16(ax.v, b0.v, accr[rt], 0, 0, 0);
        accz[rt] = __builtin_amdgcn_mfma_f32_16x16x32_bf16(ax.v, b1.v, accz[rt], 0, 0, 0);
        accn[rt] = __builtin_amdgcn_mfma_f32_16x16x32_bf16(ax.v, b2.v, accn[rt], 0, 0, 0);
      }
    }

    // ---- gh = h_{t-1} @ w_hh^T  (A from LDS parity buffer) ----
    if (t > 0) {
      const unsigned* sh = s_h + ((t - 1) & 1) * 8448;
#pragma unroll
      for (int kt = 0; kt < 8; ++kt) {
        U4 b0, b1, b2;
        b0.v4 = *(const u32x4*)(BhhW + kt * 256);
        b1.v4 = *(const u32x4*)(BhhW + (8 + kt) * 256);
        b2.v4 = *(const u32x4*)(BhhW + (16 + kt) * 256);
#pragma unroll
        for (int rt = 0; rt < 4; ++rt) {
          U4 ah;
          ah.v4 = *(const u32x4*)(sh + (rt * 16 + lo) * 132 + kt * 16 + quad * 4);
          accr[rt] = __builtin_amdgcn_mfma_f32_16x16x32_bf16(ah.v, b0.v, accr[rt], 0, 0, 0);
          accz[rt] = __builtin_amdgcn_mfma_f32_16x16x32_bf16(ah.v, b1.v, accz[rt], 0, 0, 0);
          acchn[rt] = __builtin_amdgcn_mfma_f32_16x16x32_bf16(ah.v, b2.v, acchn[rt], 0, 0, 0);
        }
      }
    }

    // ---- GRU gates (fp32, fast sigmoid/tanh) ----
#pragma unroll
    for (int rt = 0; rt < 4; ++rt) {
#pragma unroll
      for (int i = 0; i < 4; ++i) {
        float r = fsigmoid(accr[rt][i] + br);
        float z = fsigmoid(accz[rt][i] + bz);
        float n = ftanh(accn[rt][i] + bin + r * (acchn[rt][i] + bhn));
        h_own[rt][i] = (1.f - z) * n + z * h_own[rt][i];
      }
    }

    // ---- publish h2 -> LDS parity (t&1); one barrier; skip on final step ----
    if (t + 1 < T) {
      unsigned* shw = s_h + (t & 1) * 8448;
#pragma unroll
      for (int rt = 0; rt < 4; ++rt) {
#pragma unroll
        for (int i = 0; i < 4; ++i) {
          unsigned short mb = f2bf(h_own[rt][i]);
          int other = __shfl_xor((int)(unsigned)mb, 1);
          if ((lane & 1) == 0) {
            unsigned pack = (unsigned)mb | (((unsigned)other & 0xffffu) << 16);
            shw[(rt * 16 + quad * 4 + i) * 132 + wave * 8 + (lo >> 1)] = pack;
          }
        }
      }
      __syncthreads();
    }

    // ---- eos extraction ----
    if (!isq) {
      if (t >= warm) {
        int s = t - warm;
#pragma unroll
        for (int rt = 0; rt < 4; ++rt)
#pragma unroll
          for (int i = 0; i < 4; ++i) {
            int m = rt * 16 + quad * 4 + i;
            if (m < 50 && s_idx[m] == s)
              mem_slots[(size_t)(p * 50 + m) * 256 + col] = h_own[rt][i];
          }
      }
    } else {
#pragma unroll
      for (int rt = 0; rt < 4; ++rt)
#pragma unroll
        for (int i = 0; i < 4; ++i) {
          int bb = rt * 16 + quad * 4 + i;
          if (s_idx[bb] == t)
            real_q[(size_t)bb * 256 + col] = h_own[rt][i];
        }
    }
  }
}

// ---------------- mem_key = memory_slots @ w_m^T  [3200,256]x[256,256] ----------------
__global__ __launch_bounds__(256) void memkey_k(const float* __restrict__ slots,
                                                const float* __restrict__ w_m,
                                                float* __restrict__ mem_key) {
  __shared__ float A[4096];
  int tid = threadIdx.x;
  int r0 = blockIdx.x * 16;
  for (int i = tid; i < 4096; i += 256) A[i] = slots[(size_t)r0 * 256 + i];
  __syncthreads();
  float acc[16];
#pragma unroll
  for (int r = 0; r < 16; ++r) acc[r] = 0.f;
  const float* wr = w_m + (size_t)tid * 256;
  for (int k = 0; k < 256; ++k) {
    float wv = wr[k];
#pragma unroll
    for (int r = 0; r < 16; ++r) acc[r] += A[r * 256 + k] * wv;
  }
  for (int r = 0; r < 16; ++r) mem_key[(size_t)(r0 + r) * 256 + tid] = acc[r];
}

// ---------------- 3-hop attention over memory slots (one block per b) ----------------
__global__ __launch_bounds__(256) void hops_k(const float* __restrict__ mem_key,
                                              const float* __restrict__ slots,
                                              const float* __restrict__ rq,
                                              const float* __restrict__ ft_w1,
                                              const float* __restrict__ ft_b1,
                                              const float* __restrict__ ft_w2,
                                              const float* __restrict__ ft_b2,
                                              float* __restrict__ bufs) {
  int b = blockIdx.x;
  int tid = threadIdx.x;
  int lane = tid & 63;
  int wv = tid >> 6;
  __shared__ float ok[256], attn[64], bufl[256], h1[256];
  ok[tid] = rq[(size_t)b * 256 + tid];
  __syncthreads();
  const float* key = mem_key + (size_t)b * 50 * 256;
  const float* slt = slots + (size_t)b * 50 * 256;
  for (int hop = 0; hop < 3; ++hop) {
    for (int m = wv; m < 50; m += 4) {
      const float* kr = key + m * 256;
      float p = kr[lane] * ok[lane] + kr[lane + 64] * ok[lane + 64] +
                kr[lane + 128] * ok[lane + 128] + kr[lane + 192] * ok[lane + 192];
      for (int off = 32; off; off >>= 1) p += __shfl_down(p, off);
      if (lane == 0) attn[m] = p * 0.0625f;   // scale = 1/sqrt(256)
    }
    __syncthreads();
    if (tid == 0) {
      float mx = -1e30f;
      for (int m = 0; m < 50; ++m) mx = fmaxf(mx, attn[m]);
      float sm = 0.f;
      for (int m = 0; m < 50; ++m) { float e = __expf(attn[m] - mx); attn[m] = e; sm += e; }
      float inv = 1.f / sm;
      for (int m = 0; m < 50; ++m) attn[m] *= inv;
    }
    __syncthreads();
    float acc = 0.f;
    for (int m = 0; m < 50; ++m) acc += attn[m] * slt[m * 256 + tid];
    bufl[tid] = acc;
    bufs[(size_t)(b * 3 + hop) * 256 + tid] = acc;
    __syncthreads();
    float a1 = ft_b1[tid];
    const float* wr = ft_w1 + (size_t)tid * 256;
    for (int k = 0; k < 256; ++k) a1 += wr[k] * bufl[k];
    h1[tid] = fmaxf(a1, 0.f);
    __syncthreads();
    float a2 = ft_b2[tid];
    const float* w2r = ft_w2 + (size_t)tid * 256;
    for (int k = 0; k < 256; ++k) a2 += w2r[k] * h1[k];
    __syncthreads();
    ok[tid] = a2;
    __syncthreads();
  }
}

// ---------------- relation layer 1: t1 = relu(comb @ g_w1^T + g_b1) [576,768] ----------------
__global__ __launch_bounds__(256) void g1_k(const float* __restrict__ bufs,
                                            const float* __restrict__ rq,
                                            const float* __restrict__ w,
                                            const float* __restrict__ bias,
                                            float* __restrict__ out) {
  __shared__ float A[4 * 768];
  int tid = threadIdx.x;
  int r0 = blockIdx.x * 4;
  for (int i = tid; i < 4 * 768; i += 256) {
    int row = r0 + i / 768, k = i % 768;
    int bb = row / 9, p = row % 9;
    float v;
    if (k < 256)      v = bufs[(size_t)(bb * 3 + p % 3) * 256 + k];
    else if (k < 512) v = bufs[(size_t)(bb * 3 + p / 3) * 256 + (k - 256)];
    else              v = rq[(size_t)bb * 256 + (k - 512)];
    A[i] = v;
  }
  __syncthreads();
  for (int cc = 0; cc < 3; ++cc) {
    int c = cc * 256 + tid;
    float a0 = 0.f, a1 = 0.f, a2 = 0.f, a3 = 0.f;
    const float* wr = w + (size_t)c * 768;
    for (int k = 0; k < 768; ++k) {
      float wvl = wr[k];
      a0 += A[k] * wvl; a1 += A[768 + k] * wvl;
      a2 += A[1536 + k] * wvl; a3 += A[2304 + k] * wvl;
    }
    float bv = bias[c];
    out[(size_t)(r0 + 0) * 768 + c] = fmaxf(a0 + bv, 0.f);
    out[(size_t)(r0 + 1) * 768 + c] = fmaxf(a1 + bv, 0.f);
    out[(size_t)(r0 + 2) * 768 + c] = fmaxf(a2 + bv, 0.f);
    out[(size_t)(r0 + 3) * 768 + c] = fmaxf(a3 + bv, 0.f);
  }
}

// ---------------- relation layer 2: t2 = relu(t1 @ g_w2^T + g_b2) ----------------
__global__ __launch_bounds__(256) void g2_k(const float* __restrict__ t1,
                                            const float* __restrict__ w,
                                            const float* __restrict__ bias,
                                            float* __restrict__ out) {
  __shared__ float A[4 * 768];
  int tid = threadIdx.x;
  int r0 = blockIdx.x * 4;
  for (int i = tid; i < 4 * 768; i += 256) A[i] = t1[(size_t)r0 * 768 + i];
  __syncthreads();
  for (int cc = 0; cc < 3; ++cc) {
    int c = cc * 256 + tid;
    float a0 = 0.f, a1 = 0.f, a2 = 0.f, a3 = 0.f;
    const float* wr = w + (size_t)c * 768;
    for (int k = 0; k < 768; ++k) {
      float wvl = wr[k];
      a0 += A[k] * wvl; a1 += A[768 + k] * wvl;
      a2 += A[1536 + k] * wvl; a3 += A[2304 + k] * wvl;
    }
    float bv = bias[c];
    out[(size_t)(r0 + 0) * 768 + c] = fmaxf(a0 + bv, 0.f);
    out[(size_t)(r0 + 1) * 768 + c] = fmaxf(a1 + bv, 0.f);
    out[(size_t)(r0 + 2) * 768 + c] = fmaxf(a2 + bv, 0.f);
    out[(size_t)(r0 + 3) * 768 + c] = fmaxf(a3 + bv, 0.f);
  }
}

// ---------------- g-sum + f MLP -> reason [64,256] ----------------
__global__ __launch_bounds__(256) void reason_k(const float* __restrict__ t2,
                                                const float* __restrict__ f_w1,
                                                const float* __restrict__ f_b1,
                                                const float* __restrict__ f_w2,
                                                const float* __restrict__ f_b2,
                                                float* __restrict__ reason) {
  int b = blockIdx.x;
  int tid = threadIdx.x;
  __shared__ float gs[768], h1[768];
  for (int j = tid; j < 768; j += 256) {
    float s = 0.f;
    for (int p = 0; p < 9; ++p) s += t2[(size_t)(b * 9 + p) * 768 + j];
    gs[j] = s;
  }
  __syncthreads();
  for (int jc = 0; jc < 3; ++jc) {
    int j = jc * 256 + tid;
    float a = f_b1[j];
    const float* wr = f_w1 + (size_t)j * 768;
    for (int k = 0; k < 768; ++k) a += wr[k] * gs[k];
    h1[j] = fmaxf(a, 0.f);
  }
  __syncthreads();
  {
    int j = tid;
    float a = f_b2[j];
    const float* wr = f_w2 + (size_t)j * 768;
    for (int k = 0; k < 768; ++k) a += wr[k] * h1[k];
    reason[(size_t)b * 256 + j] = a;
  }
}

// ---------------- out = reason @ v_w^T  [64,50000] ----------------
__global__ __launch_bounds__(256) void vocab_k(const float* __restrict__ reason,
                                               const float* __restrict__ v_w,
                                               float* __restrict__ out) {
  __shared__ float A[32 * 256];
  int tid = threadIdx.x;
  int c = blockIdx.x * 256 + tid;
  for (int bc = 0; bc < 2; ++bc) {
    for (int i = tid; i < 32 * 256; i += 256) A[i] = reason[bc * 32 * 256 + i];
    __syncthreads();
    if (c < 50000) {
      float acc[32];
#pragma unroll
      for (int r = 0; r < 32; ++r) acc[r] = 0.f;
      const float* wr = v_w + (size_t)c * 256;
      for (int k = 0; k < 256; ++k) {
        float wvl = wr[k];
#pragma unroll
        for (int r = 0; r < 32; ++r) acc[r] += A[r * 256 + k] * wvl;
      }
      for (int r = 0; r < 32; ++r) out[(size_t)(bc * 32 + r) * 50000 + c] = acc[r];
    }
    __syncthreads();
  }
}

// ---------------- launch ----------------
extern "C" void kernel_launch(void* const* d_in, const int* in_sizes, int n_in,
                              void* d_out, int out_size, void* d_ws, size_t ws_size,
                              hipStream_t stream) {
  (void)in_sizes; (void)n_in; (void)out_size; (void)ws_size;
  const int*   story = (const int*)d_in[0];
  const int*   query = (const int*)d_in[1];
  const float* embed = (const float*)d_in[2];
  const float* w_ih  = (const float*)d_in[3];
  const float* w_hh  = (const float*)d_in[4];
  const float* b_ih  = (const float*)d_in[5];
  const float* b_hh  = (const float*)d_in[6];
  const float* w_m   = (const float*)d_in[7];
  const float* ft_w1 = (const float*)d_in[8];
  const float* ft_b1 = (const float*)d_in[9];
  const float* ft_w2 = (const float*)d_in[10];
  const float* ft_b2 = (const float*)d_in[11];
  const float* g_w1  = (const float*)d_in[12];
  const float* g_b1  = (const float*)d_in[13];
  const float* g_w2  = (const float*)d_in[14];
  const float* g_b2  = (const float*)d_in[15];
  const float* f_w1  = (const float*)d_in[16];
  const float* f_b1  = (const float*)d_in[17];
  const float* f_w2  = (const float*)d_in[18];
  const float* f_b2  = (const float*)d_in[19];
  const float* v_w   = (const float*)d_in[20];
  float* out = (float*)d_out;

  char* ws = (char*)d_ws;
  unsigned* Xs      = (unsigned*)(ws + 0);          // 20,971,520 B
  unsigned* Xq      = (unsigned*)(ws + 20971520);   //    327,680 B
  unsigned* Bih_bf  = (unsigned*)(ws + 21299200);   //    196,608 B
  unsigned* Bhh_bf  = (unsigned*)(ws + 21495808);   //    393,216 B
  int*      idx_s   = (int*)(ws + 21889024);        //     12,800 B
  int*      qidx    = (int*)(ws + 21901824);        //        256 B
  float*    mslots  = (float*)(ws + 21902080);      //  3,276,800 B
  float*    real_q  = (float*)(ws + 25178880);      //     65,536 B  (end ~25.2 MB)
  // post-GRU overlay inside the (dead) Xs region:
  float*    mem_key = (float*)(ws + 0);             //  3,276,800 B
  float*    bufs    = (float*)(ws + 3276800);       //    196,608 B
  float*    t1      = (float*)(ws + 3473408);       //  1,769,472 B
  float*    t2      = (float*)(ws + 5242880);       //  1,769,472 B
  float*    reason  = (float*)(ws + 7012352);       //     65,536 B

  idx_k<<<13, 256, 0, stream>>>(story, query, idx_s, qidx);
  wconv_k<<<576, 256, 0, stream>>>(w_ih, w_hh, Bih_bf, Bhh_bf);
  gather_k<<<20800, 256, 0, stream>>>(story, query, embed, Xs, Xq);
  gru_k<<<65, 1024, 0, stream>>>(Bih_bf, Bhh_bf, b_ih, b_hh, Xs, Xq,
                                 idx_s, qidx, mslots, real_q);
  memkey_k<<<200, 256, 0, stream>>>(mslots, w_m, mem_key);
  hops_k<<<64, 256, 0, stream>>>(mem_key, mslots, real_q,
                                 ft_w1, ft_b1, ft_w2, ft_b2, bufs);
  g1_k<<<144, 256, 0, stream>>>(bufs, real_q, g_w1, g_b1, t1);
  g2_k<<<144, 256, 0, stream>>>(t1, g_w2, g_b2, t2);
  reason_k<<<64, 256, 0, stream>>>(t2, f_w1, f_b1, f_w2, f_b2, reason);
  vocab_k<<<196, 256, 0, stream>>>(reason, v_w, out);
}